// Round 1
// baseline (235.270 us; speedup 1.0000x reference)
//
#include <hip/hip_runtime.h>
#include <hip/hip_bf16.h>
#include <cstdint>
#include <cstddef>

// ---- problem constants ----
#define NIN   2048
#define RANK  64
#define R2    128      // 2*RANK
#define NROWS 16384    // 8*2048 flattened batch*seq rows

typedef __bf16 bf16x8 __attribute__((ext_vector_type(8)));
typedef float  f32x4  __attribute__((ext_vector_type(4)));
typedef unsigned short u16x8 __attribute__((ext_vector_type(8)));

__device__ __forceinline__ unsigned short f2bf(float f) {
  union { float f; unsigned u; } x; x.f = f;
  return (unsigned short)((x.u + 0x7fffu + ((x.u >> 16) & 1u)) >> 16);
}

// ---- 1) MbfT[n][k] = bf16(M[k][n]), M = [U V] ----
__global__ void k_convM(const float* __restrict__ U, const float* __restrict__ V,
                        unsigned short* __restrict__ MbfT) {
  int idx = blockIdx.x * 256 + threadIdx.x;   // n*2048 + k
  int n = idx >> 11, k = idx & 2047;
  float v = (n < RANK) ? U[(size_t)k * RANK + n] : V[(size_t)k * RANK + (n - RANK)];
  MbfT[idx] = f2bf(v);
}

// ---- 2) G = J * (M^T M), fp32 exact-ish ----
__global__ void k_SG(const float* __restrict__ U, const float* __restrict__ V,
                     float* __restrict__ G) {
  int b = blockIdx.x;                  // 64 blocks, 16x16 tile each
  int bi = b >> 3, bj = b & 7;
  int ty = threadIdx.x >> 4, tx = threadIdx.x & 15;
  int i = bi * 16 + ty, j = bj * 16 + tx;
  const float* Ai = (i < RANK) ? (U + i) : (V + (i - RANK));  // column i of M, stride 64
  const float* Aj = (j < RANK) ? (U + j) : (V + (j - RANK));
  float acc = 0.f;
  for (int k = 0; k < NIN; ++k) acc += Ai[(size_t)k * RANK] * Aj[(size_t)k * RANK];
  // G = J*S:  G[i'] row:  i<64 -> G[i+64][j] = -S[i][j];  i>=64 handled by symmetry of loop
  if (i < RANK) G[(i + RANK) * R2 + j] = -acc;
  else          G[(i - RANK) * R2 + j] =  acc;
}

// ---- 3) generic small 128x128 GEMM: O = (A + a*I)(B + b*I), fp32 ----
struct SOp { const float* A; const float* B; float* O; float a, b; };
struct SOps { SOp op[3]; };
__global__ void k_small(SOps ops) {
  SOp o = ops.op[blockIdx.x >> 6];     // 64 blocks per op
  int t = blockIdx.x & 63;
  int i = (t >> 3) * 16 + (threadIdx.x >> 4);
  int j = (t & 7) * 16 + (threadIdx.x & 15);
  float acc = 0.f;
  for (int k = 0; k < R2; ++k) {
    float av = o.A[i * R2 + k]; if (k == i) av += o.a;
    float bv = o.B[k * R2 + j]; if (k == j) bv += o.b;
    acc += av * bv;
  }
  o.O[i * R2 + j] = acc;
}

// ---- 4) Dbf = bf16( M * ((2H - G15) * J) ),  2048x128 row-major ----
__global__ void k_D(const float* __restrict__ U, const float* __restrict__ V,
                    const float* __restrict__ H, const float* __restrict__ G15,
                    unsigned short* __restrict__ Dbf) {
  int idx = blockIdx.x * 256 + threadIdx.x;  // i*128 + j, i < 2048
  int i = idx >> 7, j = idx & 127;
  int jj = (j < RANK) ? (j + RANK) : (j - RANK);
  float sgn = (j < RANK) ? -1.f : 1.f;
  float acc = 0.f;
  for (int k = 0; k < R2; ++k) {
    float m = (k < RANK) ? U[(size_t)i * RANK + k] : V[(size_t)i * RANK + (k - RANK)];
    float t = 2.f * H[k * R2 + jj] - G15[k * R2 + jj];
    acc += m * (sgn * t);
  }
  Dbf[idx] = f2bf(acc);
}

// ---- 5) T1bf = bf16(input @ M)  [16384 x 128], MFMA bf16, K=2048 ----
__global__ __launch_bounds__(256) void k_T1(const float* __restrict__ input,
                                            const unsigned short* __restrict__ MbfT,
                                            unsigned short* __restrict__ T1bf) {
  __shared__ __align__(16) unsigned char sA[32 * 256];    // [r][128k] bf16, XOR-swizzled
  __shared__ __align__(16) unsigned char sB[128 * 256];   // [col][128k] bf16, XOR-swizzled
  const int tid = threadIdx.x;
  const int row0 = blockIdx.x * 32;
  const int lane = tid & 63, w = tid >> 6;
  const int lr = lane & 15, lg = lane >> 4;
  f32x4 acc[2][2] = {};
  for (int kt = 0; kt < 16; ++kt) {
    __syncthreads();
    // stage A: 32 rows x 128 k, fp32 -> bf16
#pragma unroll
    for (int c = 0; c < 2; ++c) {
      int ch = tid + 256 * c;            // 0..511 chunks of 8 elems
      int r = ch >> 4, kc = ch & 15;
      const float* src = input + (size_t)(row0 + r) * NIN + kt * 128 + kc * 8;
      float4 f0 = *(const float4*)src;
      float4 f1 = *(const float4*)(src + 4);
      u16x8 h;
      h[0] = f2bf(f0.x); h[1] = f2bf(f0.y); h[2] = f2bf(f0.z); h[3] = f2bf(f0.w);
      h[4] = f2bf(f1.x); h[5] = f2bf(f1.y); h[6] = f2bf(f1.z); h[7] = f2bf(f1.w);
      *(u16x8*)(sA + r * 256 + ((kc * 16) ^ ((r & 7) << 4))) = h;
    }
    // stage B: 128 cols x 128 k bf16 from MbfT (rows of MbfT are columns of M)
#pragma unroll
    for (int c = 0; c < 8; ++c) {
      int ch = tid + 256 * c;            // 0..2047
      int col = ch >> 4, kc = ch & 15;
      u16x8 h = *(const u16x8*)(MbfT + (size_t)col * NIN + kt * 128 + kc * 8);
      *(u16x8*)(sB + col * 256 + ((kc * 16) ^ ((col & 7) << 4))) = h;
    }
    __syncthreads();
#pragma unroll
    for (int ks = 0; ks < 4; ++ks) {
      bf16x8 a[2], b[2];
#pragma unroll
      for (int m = 0; m < 2; ++m) {
        int r = m * 16 + lr, kc = ks * 4 + lg;
        a[m] = *(const bf16x8*)(sA + r * 256 + ((kc * 16) ^ ((r & 7) << 4)));
      }
#pragma unroll
      for (int n = 0; n < 2; ++n) {
        int cx = w * 32 + n * 16 + lr, kc = ks * 4 + lg;
        b[n] = *(const bf16x8*)(sB + cx * 256 + ((kc * 16) ^ ((cx & 7) << 4)));
      }
#pragma unroll
      for (int m = 0; m < 2; ++m)
#pragma unroll
        for (int n = 0; n < 2; ++n)
          acc[m][n] = __builtin_amdgcn_mfma_f32_16x16x32_bf16(a[m], b[n], acc[m][n], 0, 0, 0);
    }
  }
  // epilogue: C/D layout col=lane&15, row=(lane>>4)*4+reg
#pragma unroll
  for (int m = 0; m < 2; ++m)
#pragma unroll
    for (int n = 0; n < 2; ++n)
#pragma unroll
      for (int r = 0; r < 4; ++r) {
        int grow = row0 + m * 16 + lg * 4 + r;
        int gcol = w * 32 + n * 16 + lr;
        T1bf[(size_t)grow * R2 + gcol] = f2bf(acc[m][n][r]);
      }
}

// ---- 6) out = input + T1 @ D^T   [16384 x 2048], MFMA bf16, K=128 ----
__global__ __launch_bounds__(256) void k_OUT(const float* __restrict__ input,
                                             const unsigned short* __restrict__ T1bf,
                                             const unsigned short* __restrict__ Dbf,
                                             float* __restrict__ out) {
  __shared__ __align__(16) unsigned char sA[128 * 256];   // T1 tile [r][128k]
  __shared__ __align__(16) unsigned char sB[128 * 256];   // D  tile [c][128k]
  const int tid = threadIdx.x;
  const int rb = blockIdx.x >> 4, cb = blockIdx.x & 15;
  const int row0 = rb * 128, col0 = cb * 128;
  const int lane = tid & 63, w = tid >> 6;
  const int wr = w >> 1, wc = w & 1;
  const int lr = lane & 15, lg = lane >> 4;
#pragma unroll
  for (int c = 0; c < 8; ++c) {
    int ch = tid + 256 * c;              // 0..2047
    int r = ch >> 4, kc = ch & 15;
    u16x8 ha = *(const u16x8*)(T1bf + (size_t)(row0 + r) * R2 + kc * 8);
    *(u16x8*)(sA + r * 256 + ((kc * 16) ^ ((r & 7) << 4))) = ha;
    u16x8 hb = *(const u16x8*)(Dbf + (size_t)(col0 + r) * R2 + kc * 8);
    *(u16x8*)(sB + r * 256 + ((kc * 16) ^ ((r & 7) << 4))) = hb;
  }
  __syncthreads();
  f32x4 acc[4][4] = {};
#pragma unroll
  for (int ks = 0; ks < 4; ++ks) {
    bf16x8 a[4], b[4];
#pragma unroll
    for (int m = 0; m < 4; ++m) {
      int r = wr * 64 + m * 16 + lr, kc = ks * 4 + lg;
      a[m] = *(const bf16x8*)(sA + r * 256 + ((kc * 16) ^ ((r & 7) << 4)));
    }
#pragma unroll
    for (int n = 0; n < 4; ++n) {
      int cx = wc * 64 + n * 16 + lr, kc = ks * 4 + lg;
      b[n] = *(const bf16x8*)(sB + cx * 256 + ((kc * 16) ^ ((cx & 7) << 4)));
    }
#pragma unroll
    for (int m = 0; m < 4; ++m)
#pragma unroll
      for (int n = 0; n < 4; ++n)
        acc[m][n] = __builtin_amdgcn_mfma_f32_16x16x32_bf16(a[m], b[n], acc[m][n], 0, 0, 0);
  }
  // epilogue: out = acc + input
#pragma unroll
  for (int m = 0; m < 4; ++m) {
#pragma unroll
    for (int r = 0; r < 4; ++r) {
      int grow = row0 + wr * 64 + m * 16 + lg * 4 + r;
      const float* inrow = input + (size_t)grow * NIN + col0;
      float* outrow = out + (size_t)grow * NIN + col0;
#pragma unroll
      for (int n = 0; n < 4; ++n) {
        int gcol = wc * 64 + n * 16 + lr;
        outrow[gcol] = acc[m][n][r] + inrow[gcol];
      }
    }
  }
}

extern "C" void kernel_launch(void* const* d_in, const int* in_sizes, int n_in,
                              void* d_out, int out_size, void* d_ws, size_t ws_size,
                              hipStream_t stream) {
  const float* input = (const float*)d_in[0];
  const float* U     = (const float*)d_in[1];
  const float* V     = (const float*)d_in[2];
  float* out = (float*)d_out;
  char* ws = (char*)d_ws;

  // workspace layout
  float* mats = (float*)ws;                       // 10 x 128x128 fp32 = 640 KB
  float* G   = mats + 0 * 16384;
  float* G2  = mats + 1 * 16384;
  float* G3  = mats + 2 * 16384;
  float* G4  = mats + 3 * 16384;
  float* G7  = mats + 4 * 16384;
  float* G8  = mats + 5 * 16384;
  float* H12 = mats + 6 * 16384;
  float* H124= mats + 7 * 16384;
  float* H   = mats + 8 * 16384;
  float* G15 = mats + 9 * 16384;
  unsigned short* MbfT = (unsigned short*)(ws + 10 * 65536);              // 512 KB
  unsigned short* Dbf  = (unsigned short*)(ws + 10 * 65536 + 524288);     // 512 KB
  unsigned short* T1bf = (unsigned short*)(ws + 10 * 65536 + 2 * 524288); // 4 MB

  k_convM<<<1024, 256, 0, stream>>>(U, V, MbfT);
  k_SG<<<64, 256, 0, stream>>>(U, V, G);

  { SOps o = {{ {G,  G,  G2, 0.f, 0.f}, {nullptr,nullptr,nullptr,0.f,0.f}, {nullptr,nullptr,nullptr,0.f,0.f} }};
    k_small<<<64, 256, 0, stream>>>(o); }
  { SOps o = {{ {G2, G2, G4, 0.f, 0.f}, {G2, G, G3, 0.f, 0.f}, {G, G2, H12, 1.f, 1.f} }};
    k_small<<<192, 256, 0, stream>>>(o); }
  { SOps o = {{ {G4, G4, G8, 0.f, 0.f}, {G3, G4, G7, 0.f, 0.f}, {H12, G4, H124, 0.f, 1.f} }};
    k_small<<<192, 256, 0, stream>>>(o); }
  { SOps o = {{ {G7, G8, G15, 0.f, 0.f}, {H124, G8, H, 0.f, 1.f}, {nullptr,nullptr,nullptr,0.f,0.f} }};
    k_small<<<128, 256, 0, stream>>>(o); }

  k_D<<<1024, 256, 0, stream>>>(U, V, H, G15, Dbf);
  k_T1<<<512, 256, 0, stream>>>(input, MbfT, T1bf);
  k_OUT<<<2048, 256, 0, stream>>>(input, T1bf, Dbf, out);
}

// Round 2
// 219.570 us; speedup vs baseline: 1.0715x; 1.0715x over previous
//
#include <hip/hip_runtime.h>
#include <hip/hip_bf16.h>
#include <cstdint>
#include <cstddef>

// ---- problem constants ----
#define NIN   2048
#define RANK  64
#define R2    128      // 2*RANK
#define NROWS 16384    // 8*2048 flattened batch*seq rows

typedef __bf16 bf16x8 __attribute__((ext_vector_type(8)));
typedef float  f32x4  __attribute__((ext_vector_type(4)));
typedef unsigned short u16x8 __attribute__((ext_vector_type(8)));

__device__ __forceinline__ unsigned short f2bf(float f) {
  union { float f; unsigned u; } x; x.f = f;
  return (unsigned short)((x.u + 0x7fffu + ((x.u >> 16) & 1u)) >> 16);
}

// ---- 1) MbfT[n][k] = bf16(M[k][n]), M = [U V]; also zero G for k_SG atomics ----
__global__ void k_convM(const float* __restrict__ U, const float* __restrict__ V,
                        unsigned short* __restrict__ MbfT, float* __restrict__ G) {
  int idx = blockIdx.x * 256 + threadIdx.x;   // n*2048 + k
  if (idx < R2 * R2) G[idx] = 0.f;
  int n = idx >> 11, k = idx & 2047;
  float v = (n < RANK) ? U[(size_t)k * RANK + n] : V[(size_t)k * RANK + (n - RANK)];
  MbfT[idx] = f2bf(v);
}

// ---- 2) G = J * (M^T M), fp32, K split 8 ways + atomicAdd ----
__global__ void k_SG(const float* __restrict__ U, const float* __restrict__ V,
                     float* __restrict__ G) {
  int b = blockIdx.x;                  // 512 blocks = 64 tiles x 8 ksplits
  int tile = b >> 3, ks = b & 7;
  int bi = tile >> 3, bj = tile & 7;
  int ty = threadIdx.x >> 4, tx = threadIdx.x & 15;
  int i = bi * 16 + ty, j = bj * 16 + tx;
  const float* Ai = (i < RANK) ? (U + i) : (V + (i - RANK));  // column i of M, stride 64
  const float* Aj = (j < RANK) ? (U + j) : (V + (j - RANK));
  int k0 = ks * 256;
  float acc = 0.f;
#pragma unroll 8
  for (int k = k0; k < k0 + 256; ++k) acc += Ai[(size_t)k * RANK] * Aj[(size_t)k * RANK];
  if (i < RANK) atomicAdd(&G[(i + RANK) * R2 + j], -acc);
  else          atomicAdd(&G[(i - RANK) * R2 + j],  acc);
}

// ---- 3) generic small 128x128 GEMM: O = (A + a*I)(B + b*I), fp32 ----
struct SOp { const float* A; const float* B; float* O; float a, b; };
struct SOps { SOp op[3]; };
__global__ void k_small(SOps ops) {
  SOp o = ops.op[blockIdx.x >> 6];     // 64 blocks per op
  int t = blockIdx.x & 63;
  int i = (t >> 3) * 16 + (threadIdx.x >> 4);
  int j = (t & 7) * 16 + (threadIdx.x & 15);
  float acc = 0.f;
  for (int k = 0; k < R2; ++k) {
    float av = o.A[i * R2 + k]; if (k == i) av += o.a;
    float bv = o.B[k * R2 + j]; if (k == j) bv += o.b;
    acc += av * bv;
  }
  o.O[i * R2 + j] = acc;
}

// ---- 4) Dbf = bf16( M * ((2H - G15) * J) ),  2048x128 row-major ----
__global__ void k_D(const float* __restrict__ U, const float* __restrict__ V,
                    const float* __restrict__ H, const float* __restrict__ G15,
                    unsigned short* __restrict__ Dbf) {
  int idx = blockIdx.x * 256 + threadIdx.x;  // i*128 + j, i < 2048
  int i = idx >> 7, j = idx & 127;
  int jj = (j < RANK) ? (j + RANK) : (j - RANK);
  float sgn = (j < RANK) ? -1.f : 1.f;
  float acc = 0.f;
  for (int k = 0; k < R2; ++k) {
    float m = (k < RANK) ? U[(size_t)i * RANK + k] : V[(size_t)i * RANK + (k - RANK)];
    float t = 2.f * H[k * R2 + jj] - G15[k * R2 + jj];
    acc += m * (sgn * t);
  }
  Dbf[idx] = f2bf(acc);
}

// ---- 5) T1bf = bf16(input @ M)  [16384 x 128], no-LDS MFMA, K split across waves ----
// grid 1024 blocks x 256 threads. Block = 16 rows. Wave w handles K in [w*512,(w+1)*512).
__global__ __launch_bounds__(256) void k_T1(const float* __restrict__ input,
                                            const unsigned short* __restrict__ MbfT,
                                            unsigned short* __restrict__ T1bf) {
  __shared__ float buf[4][128][18];   // [ksplit][col][row], pad 18 for banks; 36.9 KB
  const int tid = threadIdx.x, lane = tid & 63, w = tid >> 6;
  const int lr = lane & 15, lg = lane >> 4;
  const int row0 = blockIdx.x * 16;

  f32x4 acc[8] = {};
  const float* arow = input + (size_t)(row0 + lr) * NIN + w * 512 + lg * 8;
  const unsigned short* bbase = MbfT + (size_t)lr * NIN + w * 512 + lg * 8;

#pragma unroll 2
  for (int kt = 0; kt < 16; ++kt) {
    float4 a0 = *(const float4*)(arow + kt * 32);
    float4 a1 = *(const float4*)(arow + kt * 32 + 4);
    bf16x8 af;
    af[0] = (__bf16)a0.x; af[1] = (__bf16)a0.y; af[2] = (__bf16)a0.z; af[3] = (__bf16)a0.w;
    af[4] = (__bf16)a1.x; af[5] = (__bf16)a1.y; af[6] = (__bf16)a1.z; af[7] = (__bf16)a1.w;
#pragma unroll
    for (int n = 0; n < 8; ++n) {
      bf16x8 bf_ = *(const bf16x8*)(bbase + kt * 32 + (size_t)n * 16 * NIN);
      acc[n] = __builtin_amdgcn_mfma_f32_16x16x32_bf16(af, bf_, acc[n], 0, 0, 0);
    }
  }
  // write partials to LDS: C/D layout row = lg*4+r, col = n*16+lr
#pragma unroll
  for (int n = 0; n < 8; ++n) {
    int col = n * 16 + lr;
    float2 p0 = { acc[n][0], acc[n][1] };
    float2 p1 = { acc[n][2], acc[n][3] };
    *(float2*)&buf[w][col][lg * 4]     = p0;
    *(float2*)&buf[w][col][lg * 4 + 2] = p1;
  }
  __syncthreads();
  // reduce 4 K-partials and store bf16
  int r = tid >> 4, c0 = (tid & 15) * 8;
  u16x8 o;
#pragma unroll
  for (int i = 0; i < 8; ++i) {
    float s = buf[0][c0 + i][r] + buf[1][c0 + i][r] + buf[2][c0 + i][r] + buf[3][c0 + i][r];
    o[i] = f2bf(s);
  }
  *(u16x8*)(T1bf + (size_t)(row0 + r) * R2 + c0) = o;
}

// ---- 6) out = input + T1 @ D^T   [16384 x 2048], no-LDS MFMA, K=128 ----
// grid 2048 blocks x 256 threads; block tile 128x128; wave quadrant 64x64.
__global__ __launch_bounds__(256) void k_OUT(const float* __restrict__ input,
                                             const unsigned short* __restrict__ T1bf,
                                             const unsigned short* __restrict__ Dbf,
                                             float* __restrict__ out) {
  const int tid = threadIdx.x, lane = tid & 63, w = tid >> 6;
  const int wr = w >> 1, wc = w & 1;
  const int lr = lane & 15, lg = lane >> 4;
  const int rb = blockIdx.x >> 4, cb = blockIdx.x & 15;
  const int row0 = rb * 128 + wr * 64, col0 = cb * 128 + wc * 64;

  f32x4 acc[4][4] = {};
#pragma unroll
  for (int kt = 0; kt < 4; ++kt) {
    bf16x8 a[4], b[4];
#pragma unroll
    for (int m = 0; m < 4; ++m)
      a[m] = *(const bf16x8*)(T1bf + (size_t)(row0 + m * 16 + lr) * R2 + kt * 32 + lg * 8);
#pragma unroll
    for (int n = 0; n < 4; ++n)
      b[n] = *(const bf16x8*)(Dbf + (size_t)(col0 + n * 16 + lr) * R2 + kt * 32 + lg * 8);
#pragma unroll
    for (int m = 0; m < 4; ++m)
#pragma unroll
      for (int n = 0; n < 4; ++n)
        acc[m][n] = __builtin_amdgcn_mfma_f32_16x16x32_bf16(a[m], b[n], acc[m][n], 0, 0, 0);
  }
  // epilogue: out = acc + input
#pragma unroll
  for (int m = 0; m < 4; ++m) {
#pragma unroll
    for (int r = 0; r < 4; ++r) {
      int grow = row0 + m * 16 + lg * 4 + r;
      const float* inrow = input + (size_t)grow * NIN + col0;
      float* outrow = out + (size_t)grow * NIN + col0;
#pragma unroll
      for (int n = 0; n < 4; ++n) {
        int gcol = n * 16 + lr;
        outrow[gcol] = acc[m][n][r] + inrow[gcol];
      }
    }
  }
}

extern "C" void kernel_launch(void* const* d_in, const int* in_sizes, int n_in,
                              void* d_out, int out_size, void* d_ws, size_t ws_size,
                              hipStream_t stream) {
  const float* input = (const float*)d_in[0];
  const float* U     = (const float*)d_in[1];
  const float* V     = (const float*)d_in[2];
  float* out = (float*)d_out;
  char* ws = (char*)d_ws;

  // workspace layout
  float* mats = (float*)ws;                       // 10 x 128x128 fp32 = 640 KB
  float* G   = mats + 0 * 16384;
  float* G2  = mats + 1 * 16384;
  float* G3  = mats + 2 * 16384;
  float* G4  = mats + 3 * 16384;
  float* G7  = mats + 4 * 16384;
  float* G8  = mats + 5 * 16384;
  float* H12 = mats + 6 * 16384;
  float* H124= mats + 7 * 16384;
  float* H   = mats + 8 * 16384;
  float* G15 = mats + 9 * 16384;
  unsigned short* MbfT = (unsigned short*)(ws + 10 * 65536);              // 512 KB
  unsigned short* Dbf  = (unsigned short*)(ws + 10 * 65536 + 524288);     // 512 KB
  unsigned short* T1bf = (unsigned short*)(ws + 10 * 65536 + 2 * 524288); // 4 MB

  k_convM<<<1024, 256, 0, stream>>>(U, V, MbfT, G);
  k_SG<<<512, 256, 0, stream>>>(U, V, G);

  { SOps o = {{ {G,  G,  G2, 0.f, 0.f}, {nullptr,nullptr,nullptr,0.f,0.f}, {nullptr,nullptr,nullptr,0.f,0.f} }};
    k_small<<<64, 256, 0, stream>>>(o); }
  { SOps o = {{ {G2, G2, G4, 0.f, 0.f}, {G2, G, G3, 0.f, 0.f}, {G, G2, H12, 1.f, 1.f} }};
    k_small<<<192, 256, 0, stream>>>(o); }
  { SOps o = {{ {G4, G4, G8, 0.f, 0.f}, {G3, G4, G7, 0.f, 0.f}, {H12, G4, H124, 0.f, 1.f} }};
    k_small<<<192, 256, 0, stream>>>(o); }
  { SOps o = {{ {G7, G8, G15, 0.f, 0.f}, {H124, G8, H, 0.f, 1.f}, {nullptr,nullptr,nullptr,0.f,0.f} }};
    k_small<<<128, 256, 0, stream>>>(o); }

  k_D<<<1024, 256, 0, stream>>>(U, V, H, G15, Dbf);
  k_T1<<<1024, 256, 0, stream>>>(input, MbfT, T1bf);
  k_OUT<<<2048, 256, 0, stream>>>(input, T1bf, Dbf, out);
}

// Round 3
// 211.110 us; speedup vs baseline: 1.1144x; 1.0401x over previous
//
#include <hip/hip_runtime.h>
#include <hip/hip_bf16.h>
#include <cstdint>
#include <cstddef>

// ---- problem constants ----
#define NIN   2048
#define RANK  64
#define R2    128      // 2*RANK
#define NROWS 16384    // 8*2048 flattened batch*seq rows

typedef __bf16 bf16x8 __attribute__((ext_vector_type(8)));
typedef float  f32x4  __attribute__((ext_vector_type(4)));
typedef unsigned short u16x8 __attribute__((ext_vector_type(8)));

__device__ __forceinline__ unsigned short f2bf(float f) {
  union { float f; unsigned u; } x; x.f = f;
  return (unsigned short)((x.u + 0x7fffu + ((x.u >> 16) & 1u)) >> 16);
}

// ---- 1) MbfT[n][k] = bf16(M[k][n]), M = [U V]; also zero G for k_SG atomics ----
__global__ void k_convM(const float* __restrict__ U, const float* __restrict__ V,
                        unsigned short* __restrict__ MbfT, float* __restrict__ G) {
  int idx = blockIdx.x * 256 + threadIdx.x;   // n*2048 + k
  if (idx < R2 * R2) G[idx] = 0.f;
  int n = idx >> 11, k = idx & 2047;
  float v = (n < RANK) ? U[(size_t)k * RANK + n] : V[(size_t)k * RANK + (n - RANK)];
  MbfT[idx] = f2bf(v);
}

// ---- 2) G = J * (M^T M), fp32, K split 8 ways + atomicAdd ----
__global__ void k_SG(const float* __restrict__ U, const float* __restrict__ V,
                     float* __restrict__ G) {
  int b = blockIdx.x;                  // 512 blocks = 64 tiles x 8 ksplits
  int tile = b >> 3, ks = b & 7;
  int bi = tile >> 3, bj = tile & 7;
  int ty = threadIdx.x >> 4, tx = threadIdx.x & 15;
  int i = bi * 16 + ty, j = bj * 16 + tx;
  const float* Ai = (i < RANK) ? (U + i) : (V + (i - RANK));  // column i of M, stride 64
  const float* Aj = (j < RANK) ? (U + j) : (V + (j - RANK));
  int k0 = ks * 256;
  float acc = 0.f;
#pragma unroll 8
  for (int k = k0; k < k0 + 256; ++k) acc += Ai[(size_t)k * RANK] * Aj[(size_t)k * RANK];
  if (i < RANK) atomicAdd(&G[(i + RANK) * R2 + j], -acc);
  else          atomicAdd(&G[(i - RANK) * R2 + j],  acc);
}

// ---- 3) generic small 128x128 GEMM: O = (A + a*I)(B + b*I), fp32 ----
struct SOp { const float* A; const float* B; float* O; float a, b; };
struct SOps { SOp op[3]; };
__global__ void k_small(SOps ops) {
  SOp o = ops.op[blockIdx.x >> 6];     // 64 blocks per op
  int t = blockIdx.x & 63;
  int i = (t >> 3) * 16 + (threadIdx.x >> 4);
  int j = (t & 7) * 16 + (threadIdx.x & 15);
  float acc = 0.f;
  for (int k = 0; k < R2; ++k) {
    float av = o.A[i * R2 + k]; if (k == i) av += o.a;
    float bv = o.B[k * R2 + j]; if (k == j) bv += o.b;
    acc += av * bv;
  }
  o.O[i * R2 + j] = acc;
}

// ---- 4) Dbf = bf16( M * ((2H - G15) * J) ),  2048x128 row-major ----
__global__ void k_D(const float* __restrict__ U, const float* __restrict__ V,
                    const float* __restrict__ H, const float* __restrict__ G15,
                    unsigned short* __restrict__ Dbf) {
  int idx = blockIdx.x * 256 + threadIdx.x;  // i*128 + j, i < 2048
  int i = idx >> 7, j = idx & 127;
  int jj = (j < RANK) ? (j + RANK) : (j - RANK);
  float sgn = (j < RANK) ? -1.f : 1.f;
  float acc = 0.f;
  for (int k = 0; k < R2; ++k) {
    float m = (k < RANK) ? U[(size_t)i * RANK + k] : V[(size_t)i * RANK + (k - RANK)];
    float t = 2.f * H[k * R2 + jj] - G15[k * R2 + jj];
    acc += m * (sgn * t);
  }
  Dbf[idx] = f2bf(acc);
}

// ---- 5) fused: T1 = input@M (in LDS), then out = input + T1 @ D^T ----
// grid 1024 blocks x 256 threads; block = 16-row stripe x full 2048 cols.
__global__ __launch_bounds__(256) void k_fused(const float* __restrict__ input,
                                               const unsigned short* __restrict__ MbfT,
                                               const unsigned short* __restrict__ Dbf,
                                               float* __restrict__ out) {
  __shared__ float buf[4][128][18];                 // phase-1 K-split partials, 36.9 KB
  __shared__ __align__(16) unsigned char t1s[4096]; // T1 stripe bf16 [16][128], swizzled
  const int tid = threadIdx.x, lane = tid & 63, w = tid >> 6;
  const int lr = lane & 15, lg = lane >> 4;
  const int row0 = blockIdx.x * 16;

  // ---- phase 1: wave w computes T1 partial over K in [w*512,(w+1)*512) ----
  f32x4 acc1[8] = {};
  const float* arow = input + (size_t)(row0 + lr) * NIN + w * 512 + lg * 8;
  const unsigned short* bbase = MbfT + (size_t)lr * NIN + w * 512 + lg * 8;
#pragma unroll 2
  for (int kt = 0; kt < 16; ++kt) {
    float4 a0 = *(const float4*)(arow + kt * 32);
    float4 a1 = *(const float4*)(arow + kt * 32 + 4);
    bf16x8 af;
    af[0] = (__bf16)a0.x; af[1] = (__bf16)a0.y; af[2] = (__bf16)a0.z; af[3] = (__bf16)a0.w;
    af[4] = (__bf16)a1.x; af[5] = (__bf16)a1.y; af[6] = (__bf16)a1.z; af[7] = (__bf16)a1.w;
#pragma unroll
    for (int n = 0; n < 8; ++n) {
      bf16x8 bf_ = *(const bf16x8*)(bbase + kt * 32 + (size_t)n * 16 * NIN);
      acc1[n] = __builtin_amdgcn_mfma_f32_16x16x32_bf16(af, bf_, acc1[n], 0, 0, 0);
    }
  }
  // partials -> LDS: C layout col = n*16+lr, row = lg*4+r  (store [col][row])
#pragma unroll
  for (int n = 0; n < 8; ++n) {
    int col = n * 16 + lr;
    float2 p0 = { acc1[n][0], acc1[n][1] };
    float2 p1 = { acc1[n][2], acc1[n][3] };
    *(float2*)&buf[w][col][lg * 4]     = p0;
    *(float2*)&buf[w][col][lg * 4 + 2] = p1;
  }
  __syncthreads();
  // reduce 4 K-partials -> bf16 T1 stripe in LDS (swizzled row-major [16][128])
  {
    int r = tid >> 4, cc = tid & 15, c0 = cc * 8;
    u16x8 o8;
#pragma unroll
    for (int i = 0; i < 8; ++i) {
      float s = buf[0][c0 + i][r] + buf[1][c0 + i][r] + buf[2][c0 + i][r] + buf[3][c0 + i][r];
      o8[i] = f2bf(s);
    }
    *(u16x8*)(t1s + r * 256 + ((cc * 16) ^ ((r & 7) << 4))) = o8;
  }
  __syncthreads();

  // ---- phase 2: out[row0..+15][:] = input + T1 @ D^T, swapped-operand MFMA ----
  // b_frag (N-operand) = T1 rows: lane lr -> out-row, reused across all col-tiles
  bf16x8 bq[4];
#pragma unroll
  for (int kt = 0; kt < 4; ++kt)
    bq[kt] = *(const bf16x8*)(t1s + lr * 256 + (((kt * 4 + lg) * 16) ^ ((lr & 7) << 4)));

  const int colbase = w * 512;       // wave owns 512 cols = 32 tiles of 16
#pragma unroll 4
  for (int t = 0; t < 32; ++t) {
    int c0 = colbase + t * 16;
    const unsigned short* dp = Dbf + (size_t)(c0 + lr) * R2 + lg * 8;
    f32x4 o = {};
#pragma unroll
    for (int kt = 0; kt < 4; ++kt) {
      bf16x8 av = *(const bf16x8*)(dp + kt * 32);   // D rows = out-cols (M-operand)
      o = __builtin_amdgcn_mfma_f32_16x16x32_bf16(av, bq[kt], o, 0, 0, 0);
    }
    // C layout: out-row = row0+lr, out-cols = c0 + lg*4 + (0..3)  -> float4
    int orow = row0 + lr, ocol = c0 + lg * 4;
    float4 inv = *(const float4*)(input + (size_t)orow * NIN + ocol);
    float4 res = { o[0] + inv.x, o[1] + inv.y, o[2] + inv.z, o[3] + inv.w };
    *(float4*)(out + (size_t)orow * NIN + ocol) = res;
  }
}

extern "C" void kernel_launch(void* const* d_in, const int* in_sizes, int n_in,
                              void* d_out, int out_size, void* d_ws, size_t ws_size,
                              hipStream_t stream) {
  const float* input = (const float*)d_in[0];
  const float* U     = (const float*)d_in[1];
  const float* V     = (const float*)d_in[2];
  float* out = (float*)d_out;
  char* ws = (char*)d_ws;

  // workspace layout
  float* mats = (float*)ws;                       // 10 x 128x128 fp32 = 640 KB
  float* G   = mats + 0 * 16384;
  float* G2  = mats + 1 * 16384;
  float* G3  = mats + 2 * 16384;
  float* G4  = mats + 3 * 16384;
  float* G7  = mats + 4 * 16384;
  float* G8  = mats + 5 * 16384;
  float* H12 = mats + 6 * 16384;
  float* H124= mats + 7 * 16384;
  float* H   = mats + 8 * 16384;
  float* G15 = mats + 9 * 16384;
  unsigned short* MbfT = (unsigned short*)(ws + 10 * 65536);              // 512 KB
  unsigned short* Dbf  = (unsigned short*)(ws + 10 * 65536 + 524288);     // 512 KB

  k_convM<<<1024, 256, 0, stream>>>(U, V, MbfT, G);
  k_SG<<<512, 256, 0, stream>>>(U, V, G);

  { SOps o = {{ {G,  G,  G2, 0.f, 0.f}, {nullptr,nullptr,nullptr,0.f,0.f}, {nullptr,nullptr,nullptr,0.f,0.f} }};
    k_small<<<64, 256, 0, stream>>>(o); }
  { SOps o = {{ {G2, G2, G4, 0.f, 0.f}, {G2, G, G3, 0.f, 0.f}, {G, G2, H12, 1.f, 1.f} }};
    k_small<<<192, 256, 0, stream>>>(o); }
  { SOps o = {{ {G4, G4, G8, 0.f, 0.f}, {G3, G4, G7, 0.f, 0.f}, {H12, G4, H124, 0.f, 1.f} }};
    k_small<<<192, 256, 0, stream>>>(o); }
  { SOps o = {{ {G7, G8, G15, 0.f, 0.f}, {H124, G8, H, 0.f, 1.f}, {nullptr,nullptr,nullptr,0.f,0.f} }};
    k_small<<<128, 256, 0, stream>>>(o); }

  k_D<<<1024, 256, 0, stream>>>(U, V, H, G15, Dbf);
  k_fused<<<1024, 256, 0, stream>>>(input, MbfT, Dbf, out);
}